// Round 1
// baseline (395.802 us; speedup 1.0000x reference)
//
#include <hip/hip_runtime.h>

// CREStereo group correlation, fused: bilinear warp of right by flow + 9-wide
// horizontal sliding-window group correlation (4 groups x 64 ch), f32.
// Shapes: left/right [4,256,128,256], flow [4,2,128,256], out [4,36,128,256].

#define Bc 4
#define Cc 256
#define Hc 128
#define Wc 256
#define Gc 4
#define CG 64          // channels per group
#define WX 9           // window width (x); wy == 1
#define PX 4           // (WX/2) replicate pad in x
#define TILE 64        // output columns per block
#define COLS (TILE + WX - 1)   // 72 staged warped columns (tile + halo)

struct ColParam {
    int off00, off01, off10, off11;   // clamped corner offsets within a [H,W] plane
    float w00, w01, w10, w11;         // bilinear weights, validity folded in (zero pad)
};

__global__ __launch_bounds__(256) void crestereo_corr(
    const float* __restrict__ left, const float* __restrict__ right,
    const float* __restrict__ flow, float* __restrict__ out)
{
    __shared__ ColParam cp[COLS];
    __shared__ float wlds[CG][COLS + 1];   // +1 pad -> 73: 2-way LDS conflict only (free)

    const int t = threadIdx.x;
    const int xstart = blockIdx.x * TILE;
    const int y = blockIdx.y;
    const int b = blockIdx.z;

    // ---- per-column bilinear sampling params (shared across channels/groups) ----
    if (t < COLS) {
        int cc = xstart + t - PX;                       // replicate pad of warped tensor
        cc = cc < 0 ? 0 : (cc > Wc - 1 ? Wc - 1 : cc);
        const float fx = flow[((size_t)(b * 2 + 0) * Hc + y) * Wc + cc];
        const float fy = flow[((size_t)(b * 2 + 1) * Hc + y) * Wc + cc];
        const float X = (float)cc + fx;
        const float Y = (float)y + fy;
        const float x0f = floorf(X), y0f = floorf(Y);
        const int x0 = (int)x0f, y0 = (int)y0f;
        const int x1 = x0 + 1, y1 = y0 + 1;
        const float ax = X - x0f, ay = Y - y0f;
        const bool vx0 = (x0 >= 0) & (x0 < Wc), vx1 = (x1 >= 0) & (x1 < Wc);
        const bool vy0 = (y0 >= 0) & (y0 < Hc), vy1 = (y1 >= 0) & (y1 < Hc);
        const int x0c = min(max(x0, 0), Wc - 1), x1c = min(max(x1, 0), Wc - 1);
        const int y0c = min(max(y0, 0), Hc - 1), y1c = min(max(y1, 0), Hc - 1);
        ColParam p;
        p.off00 = y0c * Wc + x0c;  p.off01 = y0c * Wc + x1c;
        p.off10 = y1c * Wc + x0c;  p.off11 = y1c * Wc + x1c;
        p.w00 = (vx0 && vy0) ? (1.f - ax) * (1.f - ay) : 0.f;
        p.w01 = (vx1 && vy0) ? ax * (1.f - ay)         : 0.f;
        p.w10 = (vx0 && vy1) ? (1.f - ax) * ay         : 0.f;
        p.w11 = (vx1 && vy1) ? ax * ay                 : 0.f;
        cp[t] = p;
    }
    __syncthreads();

    const int lane = t & 63;
    const int w    = t >> 6;        // wave id 0..3 -> owns output cols [w*16, w*16+16)
    const int q    = lane >> 4;     // channel quarter 0..3 (16 ch each)
    const int colw = lane & 15;
    const int col  = w * 16 + colw; // output column within tile, 0..63

    for (int g = 0; g < Gc; ++g) {
        // ---- stage warped right tile for this group's 64 channels ----
        for (int it = 0; it < (CG * COLS) / 256; ++it) {   // 18 iters
            const int idx = it * 256 + t;
            const int ch = idx / COLS;
            const int cl = idx - ch * COLS;
            const ColParam p = cp[cl];
            const float* Rp = right + (size_t)(b * Cc + g * CG + ch) * (Hc * Wc);
            wlds[ch][cl] = p.w00 * Rp[p.off00] + p.w01 * Rp[p.off01]
                         + p.w10 * Rp[p.off10] + p.w11 * Rp[p.off11];
        }
        __syncthreads();

        // ---- correlation: 9 shifts, 16 channels per lane, shuffle-reduce quarters ----
        float acc[WX];
        #pragma unroll
        for (int ix = 0; ix < WX; ++ix) acc[ix] = 0.f;

        const float* Lp = left + ((size_t)(b * Cc + g * CG + q * 16) * Hc + y) * Wc
                               + xstart + col;
        #pragma unroll
        for (int c = 0; c < 16; ++c) {
            const float lv = Lp[(size_t)c * Hc * Wc];
            const float* wr = &wlds[q * 16 + c][col];
            #pragma unroll
            for (int ix = 0; ix < WX; ++ix)
                acc[ix] += lv * wr[ix];
        }
        #pragma unroll
        for (int ix = 0; ix < WX; ++ix) {
            acc[ix] += __shfl_xor(acc[ix], 16);
            acc[ix] += __shfl_xor(acc[ix], 32);
        }
        if (q == 0) {
            #pragma unroll
            for (int ix = 0; ix < WX; ++ix) {
                out[((size_t)(b * Gc * WX + g * WX + ix) * Hc + y) * Wc
                    + xstart + w * 16 + colw] = acc[ix] * (1.f / CG);
            }
        }
        __syncthreads();
    }
}

extern "C" void kernel_launch(void* const* d_in, const int* in_sizes, int n_in,
                              void* d_out, int out_size, void* d_ws, size_t ws_size,
                              hipStream_t stream) {
    const float* left  = (const float*)d_in[0];
    const float* right = (const float*)d_in[1];
    const float* flow  = (const float*)d_in[2];
    float* out = (float*)d_out;
    (void)d_ws; (void)ws_size; (void)in_sizes; (void)n_in; (void)out_size;

    dim3 grid(Wc / TILE, Hc, Bc);   // 4 x 128 x 4 = 2048 blocks
    dim3 block(256);
    hipLaunchKernelGGL(crestereo_corr, grid, block, 0, stream, left, right, flow, out);
}